// Round 2
// baseline (6054.049 us; speedup 1.0000x reference)
//
#include <hip/hip_runtime.h>
#include <cstdint>

#define BATCH 64
#define SEQ   512
#define DIN   862
#define DPAD  896
#define HID   1024
#define NG    4096

typedef _Float16 f16;
typedef __attribute__((ext_vector_type(8))) _Float16 f16x8;
typedef __attribute__((ext_vector_type(4))) float    f32x4;
typedef unsigned long long u64;

// ---------------- async global->LDS (16B per lane, wave-uniform LDS base) -------------
__device__ __forceinline__ void glds16(const f16* g, f16* l) {
    auto gp = (const __attribute__((address_space(1))) void*)(uintptr_t)g;
    auto lp = (__attribute__((address_space(3))) void*)(uint32_t)(uintptr_t)l;
    __builtin_amdgcn_global_load_lds(gp, lp, 16, 0, 0);
}

__device__ __forceinline__ float sigf(float x) {
    return __builtin_amdgcn_rcpf(1.f + __expf(-x));
}
__device__ __forceinline__ float tanh_fast(float x) {
    float xx = fminf(15.f, fmaxf(-15.f, x));
    float e = __expf(2.f * xx);
    return (e - 1.f) * __builtin_amdgcn_rcpf(e + 1.f);
}

// XG layout: [t][bs(4)][jg(64)][g(4)][bl(16)][jl(16)]  (f16, bias included)
__device__ __forceinline__ long xg_index(int t, int b, int n) {
    int bs = b >> 4, bl = b & 15;
    int g = n >> 10, jh = n & 1023;
    int jg = jh >> 4, jl = jh & 15;
    return (((((long)t * 4 + bs) * 64 + jg) * 4 + g) * 16 + bl) * 16 + jl;
}

// coherent (L2-bypassing) helpers for cross-block h exchange + leaf counters
__device__ __forceinline__ unsigned leaf_load(const unsigned* p) {
    return __hip_atomic_load((unsigned*)p, __ATOMIC_RELAXED, __HIP_MEMORY_SCOPE_AGENT);
}
__device__ __forceinline__ void leaf_add(unsigned* p) {
    __hip_atomic_fetch_add(p, 1u, __ATOMIC_RELAXED, __HIP_MEMORY_SCOPE_AGENT);
}
__device__ __forceinline__ f16x8 h_frag_load(const f16* p) {
    union { u64 u[2]; f16x8 v; } r;
    r.u[0] = __hip_atomic_load((u64*)p,     __ATOMIC_RELAXED, __HIP_MEMORY_SCOPE_AGENT);
    r.u[1] = __hip_atomic_load((u64*)p + 1, __ATOMIC_RELAXED, __HIP_MEMORY_SCOPE_AGENT);
    return r.v;
}

// ---------------- prep: fp32->fp16 conversions, padding, bias sums, barrier zero ------
__global__ __launch_bounds__(256) void prep_kernel(
    const float* __restrict__ x,
    const float* __restrict__ Wih0, const float* __restrict__ Whh0,
    const float* __restrict__ bih0, const float* __restrict__ bhh0,
    const float* __restrict__ Wih1, const float* __restrict__ Whh1,
    const float* __restrict__ bih1, const float* __restrict__ bhh1,
    f16* __restrict__ xh, f16* __restrict__ W0h, f16* __restrict__ Wh0h,
    f16* __restrict__ W1h, f16* __restrict__ Wh1h,
    float* __restrict__ b0, float* __restrict__ b1, unsigned* __restrict__ bar)
{
    long tid = (long)blockIdx.x * blockDim.x + threadIdx.x;
    long np  = (long)gridDim.x * blockDim.x;
    for (long i = tid; i < (long)BATCH * SEQ * DPAD; i += np) {
        long m = i / DPAD, k = i % DPAD;
        xh[i] = (k < DIN) ? (f16)x[m * DIN + k] : (f16)0.f;
    }
    for (long i = tid; i < (long)NG * DPAD; i += np) {
        long n = i / DPAD, k = i % DPAD;
        W0h[i] = (k < DIN) ? (f16)Wih0[n * DIN + k] : (f16)0.f;
    }
    for (long i = tid; i < (long)NG * HID; i += np) {
        Wh0h[i] = (f16)Whh0[i];
        W1h[i]  = (f16)Wih1[i];
        Wh1h[i] = (f16)Whh1[i];
    }
    for (long i = tid; i < NG; i += np) { b0[i] = bih0[i] + bhh0[i]; b1[i] = bih1[i] + bhh1[i]; }
    for (long i = tid; i < 8192; i += np) bar[i] = 0u;
}

// ---------------- f16 GEMM: gates[m][n] = A[m][:K] . Bw[n][:K] + bias[n] --------------
__global__ __launch_bounds__(256) void gemm_f16(
    const f16* __restrict__ A, const f16* __restrict__ Bw,
    const float* __restrict__ bias, f16* __restrict__ out, int K, int mode)
{
    __shared__ f16 smem[2 * 128 * 32];   // A tile | B tile, 8KB each
    const int tid  = threadIdx.x;
    const int lane = tid & 63, wave = tid >> 6;
    const int wm = wave >> 1, wn = wave & 1;
    const int quad = lane >> 4, l15 = lane & 15;
    const int bm = blockIdx.x >> 5, bn = blockIdx.x & 31;
    const long m0 = (long)bm * 128, n0 = (long)bn * 128;
    const int r4 = lane >> 2, g4 = lane & 3;

    f32x4 acc[4][4];
#pragma unroll
    for (int i = 0; i < 4; ++i)
#pragma unroll
        for (int j = 0; j < 4; ++j)
#pragma unroll
            for (int r = 0; r < 4; ++r) acc[i][j][r] = 0.f;

#pragma unroll 1
    for (int kk = 0; kk < K; kk += 32) {
#pragma unroll
        for (int c = 0; c < 2; ++c) {
            int idx = wave * 2 + c;
            int lr  = idx * 16 + r4;
            int gs  = g4 ^ ((lr >> 1) & 3);          // XOR-swizzled source granule
            glds16(A  + (m0 + lr) * (long)K + kk + gs * 8, smem + idx * 512);
            glds16(Bw + (n0 + lr) * (long)K + kk + gs * 8, smem + 4096 + idx * 512);
        }
        __syncthreads();
        f16x8 af[4], bf[4];
#pragma unroll
        for (int i = 0; i < 4; ++i) {
            int lr = 64 * wm + 16 * i + l15;
            int sl = quad ^ ((lr >> 1) & 3);
            af[i] = *(const f16x8*)(smem + lr * 32 + sl * 8);
        }
#pragma unroll
        for (int j = 0; j < 4; ++j) {
            int lr = 64 * wn + 16 * j + l15;
            int sl = quad ^ ((lr >> 1) & 3);
            bf[j] = *(const f16x8*)(smem + 4096 + lr * 32 + sl * 8);
        }
#pragma unroll
        for (int i = 0; i < 4; ++i)
#pragma unroll
            for (int j = 0; j < 4; ++j)
                acc[i][j] = __builtin_amdgcn_mfma_f32_16x16x32_f16(af[i], bf[j], acc[i][j], 0, 0, 0);
        __syncthreads();
    }

#pragma unroll
    for (int j = 0; j < 4; ++j) {
        int n = (int)n0 + 64 * wn + 16 * j + l15;
        float bv = bias[n];
#pragma unroll
        for (int i = 0; i < 4; ++i) {
#pragma unroll
            for (int r = 0; r < 4; ++r) {
                int m = (int)m0 + 64 * wm + 16 * i + quad * 4 + r;
                int t, b;
                if (mode == 1) { b = m >> 9; t = m & 511; }
                else           { t = m >> 6; b = m & 63; }
                out[xg_index(t, b, n)] = (f16)(acc[i][j][r] + bv);
            }
        }
    }
}

// ======================================================================================
// Fused 2-layer LSTM. 512 blocks: 0..255 = layer-1 role, 256..511 = layer-2 role.
// Per role, block (bs,jg) = 16 batches x 16 hidden units; 4 waves split K=1024.
// Sync: per-(role,bs) group of 64 blocks, 16 leaf counters, +16/step each.
// Wave signals its leaf after s_waitcnt vmcnt(0) drains its sc1 h-stores; consumers
// poll the 16 leaves wave-autonomously (lanes 0..15 + __all). The group poll subsumes
// the P-buffer reuse hazard (signal is program-ordered after each wave's P reads).
// Layer-2 computes W1@h1(t) + Whh1@h2(t-1) in one accumulator: Whh1 resident in regs,
// W1 streamed from L2 (static addresses, 2-chunk rolling prefetch) -> GEMM2 eliminated.
// ======================================================================================
#define IH_STEP(SS, CURB)                                                                   \
    {                                                                                       \
        _Pragma("unroll") for (int g = 0; g < 4; ++g)                                       \
            acc[g] = __builtin_amdgcn_mfma_f32_16x16x32_f16(af1[SS], CURB[g], acc[g], 0, 0, 0); \
        if (t > 0) {                                                                        \
            _Pragma("unroll") for (int g = 0; g < 4; ++g)                                   \
                acc[g] = __builtin_amdgcn_mfma_f32_16x16x32_f16(af2[SS], wf[g][SS], acc[g], 0, 0, 0); \
        }                                                                                   \
        if (SS < 6) {                                                                       \
            _Pragma("unroll") for (int g = 0; g < 4; ++g)                                   \
                CURB[g] = *(const f16x8*)(wbase[g] + (SS + 2) * 32);                        \
        }                                                                                   \
    }

__global__ __launch_bounds__(256, 2) void lstm_fused(
    const f16* __restrict__ xg1, const f16* __restrict__ Whh0,
    const f16* __restrict__ W1,  const f16* __restrict__ Whh1,
    const float* __restrict__ b1,
    f16* __restrict__ bufA, f16* __restrict__ bufB,
    float* __restrict__ out32, unsigned* __restrict__ bar)
{
    __shared__ float P[4 * 4 * 16 * 17];
    const int tid = threadIdx.x;
    const int lane = tid & 63, w = tid >> 6;
    const int quad = lane >> 4, l15 = lane & 15;
    const bool roleB = (blockIdx.x >= 256);
    const int idx = roleB ? (int)blockIdx.x - 256 : (int)blockIdx.x;
    const int bs = idx & 3, jg = idx >> 2;
    const int ks0 = 256 * w;
    unsigned* leavesA = bar + bs * 512;
    unsigned* leavesB = bar + 2048 + bs * 512;
    unsigned* myLeaf = (roleB ? leavesB : leavesA) + (((jg << 2) | w) & 15) * 32;
    const int gb = tid >> 4, gj = tid & 15;
    const int bG = bs * 16 + gb, jG = jg * 16 + gj;

    if (!roleB) {
        // ------------------------------ layer-1 role ---------------------------------
        f16x8 wf[4][8];
#pragma unroll
        for (int g = 0; g < 4; ++g) {
            const f16* Wp = Whh0 + ((long)g * HID + jg * 16 + l15) * HID + ks0 + quad * 8;
#pragma unroll
            for (int s = 0; s < 8; ++s) wf[g][s] = *(const f16x8*)(Wp + s * 32);
        }
#pragma unroll
        for (int g = 0; g < 4; ++g)
#pragma unroll
            for (int s = 0; s < 8; ++s) asm volatile("" : "+v"(wf[g][s]));

        unsigned* hwA = (unsigned*)bufA;
        float cst = 0.f;
        const f16* xq = xg1 + (((long)0 * 4 + bs) * 64 + jg) * 1024 + gb * 16 + gj;
        f16 xr0 = xq[0], xr1 = xq[256], xr2 = xq[512], xr3 = xq[768];

#pragma unroll 1
        for (int t = 0; t < SEQ; ++t) {
            if (t > 0) {                         // wait own group: h1(t-1) complete
                unsigned tgt = 16u * (unsigned)t;
                const unsigned* pp = leavesA + (lane & 15) * 32;
                for (;;) {
                    unsigned v = (lane < 16) ? leaf_load(pp) : tgt;
                    if (__all((int)(v >= tgt))) break;
                    __builtin_amdgcn_s_sleep(1);
                }
            }
            f32x4 acc[4];
#pragma unroll
            for (int g = 0; g < 4; ++g)
#pragma unroll
                for (int r = 0; r < 4; ++r) acc[g][r] = 0.f;

            if (t > 0) {
                const f16* hp = bufA + ((long)(t - 1) * BATCH + bs * 16 + l15) * HID + ks0 + quad * 8;
                f16x8 af[8];
#pragma unroll
                for (int s = 0; s < 8; ++s) af[s] = h_frag_load(hp + s * 32);
#pragma unroll
                for (int s = 0; s < 8; ++s)
#pragma unroll
                    for (int g = 0; g < 4; ++g)
                        acc[g] = __builtin_amdgcn_mfma_f32_16x16x32_f16(af[s], wf[g][s], acc[g], 0, 0, 0);
            }

#pragma unroll
            for (int g = 0; g < 4; ++g)
#pragma unroll
                for (int r = 0; r < 4; ++r)
                    P[((w * 4 + g) * 16 + quad * 4 + r) * 17 + l15] = acc[g][r];
            __syncthreads();

            float gate[4];
#pragma unroll
            for (int g = 0; g < 4; ++g) {
                float s0 = P[((0 * 4 + g) * 16 + gb) * 17 + gj];
                float s1 = P[((1 * 4 + g) * 16 + gb) * 17 + gj];
                float s2 = P[((2 * 4 + g) * 16 + gb) * 17 + gj];
                float s3 = P[((3 * 4 + g) * 16 + gb) * 17 + gj];
                gate[g] = (s0 + s1) + (s2 + s3);
            }
            float gi = gate[0] + (float)xr0;
            float gf = gate[1] + (float)xr1;
            float gg = gate[2] + (float)xr2;
            float go = gate[3] + (float)xr3;
            float si = sigf(gi), sf = sigf(gf), so = sigf(go);
            float tg = tanh_fast(gg);
            cst = sf * cst + si * tg;
            float h = so * tanh_fast(cst);

            union { f16 f; unsigned short u; } cv; cv.f = (f16)h;
            unsigned hv = cv.u;
            unsigned ov = __shfl_xor(hv, 1);
            if (!(tid & 1))
                __hip_atomic_store(&hwA[(((long)t * BATCH + bG) * HID + jG) >> 1],
                                   hv | (ov << 16), __ATOMIC_RELAXED, __HIP_MEMORY_SCOPE_AGENT);
            asm volatile("s_waitcnt vmcnt(0)" ::: "memory");
            if (lane == 0) leaf_add(myLeaf);
            if (t + 1 < SEQ) {                    // prefetch xg(t+1), hides under poll
                const f16* xn = xg1 + (((long)(t + 1) * 4 + bs) * 64 + jg) * 1024 + gb * 16 + gj;
                xr0 = xn[0]; xr1 = xn[256]; xr2 = xn[512]; xr3 = xn[768];
            }
        }
    } else {
        // ------------------------------ layer-2 role ---------------------------------
        f16x8 wf[4][8];
#pragma unroll
        for (int g = 0; g < 4; ++g) {
            const f16* Wp = Whh1 + ((long)g * HID + jg * 16 + l15) * HID + ks0 + quad * 8;
#pragma unroll
            for (int s = 0; s < 8; ++s) wf[g][s] = *(const f16x8*)(Wp + s * 32);
        }
#pragma unroll
        for (int g = 0; g < 4; ++g)
#pragma unroll
            for (int s = 0; s < 8; ++s) asm volatile("" : "+v"(wf[g][s]));

        float b1v[4];
#pragma unroll
        for (int g = 0; g < 4; ++g) b1v[g] = b1[g * HID + jG];
        const f16* wbase[4];
#pragma unroll
        for (int g = 0; g < 4; ++g)
            wbase[g] = W1 + ((long)g * HID + jg * 16 + l15) * HID + ks0 + quad * 8;
        f16x8 ihA[4], ihB[4];
#pragma unroll
        for (int g = 0; g < 4; ++g) ihA[g] = *(const f16x8*)(wbase[g]);
#pragma unroll
        for (int g = 0; g < 4; ++g) ihB[g] = *(const f16x8*)(wbase[g] + 32);

        unsigned* hwB = (unsigned*)bufB;
        float cst = 0.f;

#pragma unroll 1
        for (int t = 0; t < SEQ; ++t) {
            {   // wait: h1(t) from layer-1 group (lanes 0..15), h2(t-1) own group (16..31)
                unsigned tgtA = 16u * (unsigned)(t + 1), tgtB = 16u * (unsigned)t;
                int nact = (t > 0) ? 32 : 16;
                const unsigned* pp = (lane < 16) ? (leavesA + lane * 32)
                                                 : (leavesB + (lane & 15) * 32);
                unsigned tgt = (lane < 16) ? tgtA : tgtB;
                for (;;) {
                    unsigned v = (lane < nact) ? leaf_load(pp) : tgt;
                    if (__all((int)(v >= tgt))) break;
                    __builtin_amdgcn_s_sleep(1);
                }
            }
            f32x4 acc[4];
#pragma unroll
            for (int g = 0; g < 4; ++g)
#pragma unroll
                for (int r = 0; r < 4; ++r) acc[g][r] = 0.f;

            const f16* hp1 = bufA + ((long)t * BATCH + bs * 16 + l15) * HID + ks0 + quad * 8;
            f16x8 af1[8];
#pragma unroll
            for (int s = 0; s < 8; ++s) af1[s] = h_frag_load(hp1 + s * 32);
            f16x8 af2[8];
            if (t > 0) {
                const f16* hp2 = bufB + ((long)(t - 1) * BATCH + bs * 16 + l15) * HID + ks0 + quad * 8;
#pragma unroll
                for (int s = 0; s < 8; ++s) af2[s] = h_frag_load(hp2 + s * 32);
            }
            IH_STEP(0, ihA) IH_STEP(1, ihB) IH_STEP(2, ihA) IH_STEP(3, ihB)
            IH_STEP(4, ihA) IH_STEP(5, ihB) IH_STEP(6, ihA) IH_STEP(7, ihB)

#pragma unroll
            for (int g = 0; g < 4; ++g)
#pragma unroll
                for (int r = 0; r < 4; ++r)
                    P[((w * 4 + g) * 16 + quad * 4 + r) * 17 + l15] = acc[g][r];
            __syncthreads();

            float gate[4];
#pragma unroll
            for (int g = 0; g < 4; ++g) {
                float s0 = P[((0 * 4 + g) * 16 + gb) * 17 + gj];
                float s1 = P[((1 * 4 + g) * 16 + gb) * 17 + gj];
                float s2 = P[((2 * 4 + g) * 16 + gb) * 17 + gj];
                float s3 = P[((3 * 4 + g) * 16 + gb) * 17 + gj];
                gate[g] = ((s0 + s1) + (s2 + s3)) + b1v[g];
            }
            float si = sigf(gate[0]), sf = sigf(gate[1]), so = sigf(gate[3]);
            float tg = tanh_fast(gate[2]);
            cst = sf * cst + si * tg;
            float h = so * tanh_fast(cst);

            union { f16 f; unsigned short u; } cv; cv.f = (f16)h;
            unsigned hv = cv.u;
            unsigned ov = __shfl_xor(hv, 1);
            if (!(tid & 1))
                __hip_atomic_store(&hwB[(((long)t * BATCH + bG) * HID + jG) >> 1],
                                   hv | (ov << 16), __ATOMIC_RELAXED, __HIP_MEMORY_SCOPE_AGENT);
            out32[((long)bG * SEQ + t) * HID + jG] = h;
            asm volatile("s_waitcnt vmcnt(0)" ::: "memory");
            if (lane == 0) leaf_add(myLeaf);
            if (t + 1 < SEQ) {                    // reload W1 chunks 0,1 (L2-hit)
#pragma unroll
                for (int g = 0; g < 4; ++g) ihA[g] = *(const f16x8*)(wbase[g]);
#pragma unroll
                for (int g = 0; g < 4; ++g) ihB[g] = *(const f16x8*)(wbase[g] + 32);
            }
        }
    }
}

// ---------------- fallback path (proven round-1 kernels) ------------------------------
__device__ __forceinline__ void grid_barrier_nf(unsigned* bar, unsigned target) {
    asm volatile("s_waitcnt vmcnt(0)" ::: "memory");
    __syncthreads();
    if (threadIdx.x == 0) {
        unsigned grp = blockIdx.x >> 4;
        unsigned prev = __hip_atomic_fetch_add(&bar[grp * 32], 1u, __ATOMIC_RELAXED, __HIP_MEMORY_SCOPE_AGENT);
        if ((prev & 15u) == 15u) {
            unsigned pr = __hip_atomic_fetch_add(&bar[512], 1u, __ATOMIC_RELAXED, __HIP_MEMORY_SCOPE_AGENT);
            if ((pr & 15u) == 15u)
                __hip_atomic_store(&bar[544], target, __ATOMIC_RELAXED, __HIP_MEMORY_SCOPE_AGENT);
        }
        while (__hip_atomic_load(&bar[544], __ATOMIC_RELAXED, __HIP_MEMORY_SCOPE_AGENT) < target)
            __builtin_amdgcn_s_sleep(1);
    }
    __syncthreads();
}

__global__ __launch_bounds__(256, 1) void lstm_layer(
    const f16* __restrict__ xg, const f16* __restrict__ Whh,
    f16* __restrict__ hseq, float* __restrict__ out32, unsigned* __restrict__ bar)
{
    __shared__ float P[4 * 4 * 16 * 17];
    const int tid = threadIdx.x;
    const int lane = tid & 63, w = tid >> 6;
    const int quad = lane >> 4, l15 = lane & 15;
    const int bs = blockIdx.x & 3;
    const int jg = blockIdx.x >> 2;
    const int ks0 = 256 * w;

    f16x8 wf[4][8];
#pragma unroll
    for (int g = 0; g < 4; ++g) {
        const f16* Wp = Whh + ((long)g * HID + jg * 16 + l15) * HID + ks0 + quad * 8;
#pragma unroll
        for (int s = 0; s < 8; ++s) wf[g][s] = *(const f16x8*)(Wp + s * 32);
    }
#pragma unroll
    for (int g = 0; g < 4; ++g)
#pragma unroll
        for (int s = 0; s < 8; ++s) asm volatile("" : "+v"(wf[g][s]));

    const int gb = tid >> 4, gj = tid & 15;
    const int bG = bs * 16 + gb, jG = jg * 16 + gj;
    unsigned* hw = (unsigned*)hseq;
    float cst = 0.f;

#pragma unroll 1
    for (int t = 0; t < SEQ; ++t) {
        const f16* xp = xg + (((long)t * 4 + bs) * 64 + jg) * 1024 + gb * 16 + gj;
        float xgi = (float)xp[0];
        float xgf = (float)xp[256];
        float xgg = (float)xp[512];
        float xgo = (float)xp[768];

        f32x4 acc[4];
#pragma unroll
        for (int g = 0; g < 4; ++g)
#pragma unroll
            for (int r = 0; r < 4; ++r) acc[g][r] = 0.f;

        if (t > 0) {
            const f16* hp = hseq + ((long)(t - 1) * BATCH + bs * 16 + l15) * HID + ks0 + quad * 8;
#pragma unroll
            for (int s = 0; s < 8; ++s) {
                f16x8 af = h_frag_load(hp + s * 32);
#pragma unroll
                for (int g = 0; g < 4; ++g)
                    acc[g] = __builtin_amdgcn_mfma_f32_16x16x32_f16(af, wf[g][s], acc[g], 0, 0, 0);
            }
        }

#pragma unroll
        for (int g = 0; g < 4; ++g)
#pragma unroll
            for (int r = 0; r < 4; ++r)
                P[((w * 4 + g) * 16 + quad * 4 + r) * 17 + l15] = acc[g][r];
        __syncthreads();

        float gate[4];
#pragma unroll
        for (int g = 0; g < 4; ++g) {
            float s0 = P[((0 * 4 + g) * 16 + gb) * 17 + gj];
            float s1 = P[((1 * 4 + g) * 16 + gb) * 17 + gj];
            float s2 = P[((2 * 4 + g) * 16 + gb) * 17 + gj];
            float s3 = P[((3 * 4 + g) * 16 + gb) * 17 + gj];
            gate[g] = (s0 + s1) + (s2 + s3);
        }

        float gi = gate[0] + xgi;
        float gf = gate[1] + xgf;
        float gg = gate[2] + xgg;
        float go = gate[3] + xgo;
        float si = sigf(gi), sf = sigf(gf), so = sigf(go);
        float tg = tanh_fast(gg);
        cst = sf * cst + si * tg;
        float h = so * tanh_fast(cst);

        union { f16 f; unsigned short u; } cv; cv.f = (f16)h;
        unsigned hv = cv.u;
        unsigned ov = __shfl_xor(hv, 1);
        if (!(tid & 1))
            __hip_atomic_store(&hw[(((long)t * BATCH + bG) * HID + jG) >> 1],
                               hv | (ov << 16), __ATOMIC_RELAXED, __HIP_MEMORY_SCOPE_AGENT);
        if (out32) out32[((long)bG * SEQ + t) * HID + jG] = h;

        if (t + 1 < SEQ) grid_barrier_nf(bar, (unsigned)(t + 1));
    }
}

// ---------------- host ----------------------------------------------------------------
extern "C" void kernel_launch(void* const* d_in, const int* in_sizes, int n_in,
                              void* d_out, int out_size, void* d_ws, size_t ws_size,
                              hipStream_t stream) {
    (void)in_sizes; (void)n_in; (void)out_size;
    const float* x    = (const float*)d_in[0];
    const float* Wih0 = (const float*)d_in[1];
    const float* Whh0 = (const float*)d_in[2];
    const float* bih0 = (const float*)d_in[3];
    const float* bhh0 = (const float*)d_in[4];
    const float* Wih1 = (const float*)d_in[5];
    const float* Whh1 = (const float*)d_in[6];
    const float* bih1 = (const float*)d_in[7];
    const float* bhh1 = (const float*)d_in[8];

    char* ws = (char*)d_ws;
    size_t off = 0;
    auto alloc = [&](size_t bytes) { char* p = ws + off; off += (bytes + 255) & ~(size_t)255; return p; };
    f16*   XG   = (f16*)alloc((size_t)SEQ * BATCH * NG * 2);     // 256 MB
    f16*   xh   = (f16*)alloc((size_t)BATCH * SEQ * DPAD * 2);   // 56 MB
    f16*   h1   = (f16*)alloc((size_t)SEQ * BATCH * HID * 2);    // 64 MB (bufA)
    f16*   W0h  = (f16*)alloc((size_t)NG * DPAD * 2);
    f16*   Wh0h = (f16*)alloc((size_t)NG * HID * 2);
    f16*   W1h  = (f16*)alloc((size_t)NG * HID * 2);
    f16*   Wh1h = (f16*)alloc((size_t)NG * HID * 2);
    float* b0   = (float*)alloc((size_t)NG * 4);
    float* b1   = (float*)alloc((size_t)NG * 4);
    unsigned* bar = (unsigned*)alloc(8192 * 4);
    f16*   h2   = (f16*)alloc((size_t)SEQ * BATCH * HID * 2);    // 64 MB (bufB, fused only)
    size_t need = off;

    prep_kernel<<<dim3(2048), dim3(256), 0, stream>>>(x, Wih0, Whh0, bih0, bhh0,
                                                      Wih1, Whh1, bih1, bhh1,
                                                      xh, W0h, Wh0h, W1h, Wh1h, b0, b1, bar);

    gemm_f16<<<dim3(8192), dim3(256), 0, stream>>>(xh, W0h, b0, XG, DPAD, 1);

    int occ = 0;
    (void)hipOccupancyMaxActiveBlocksPerMultiprocessor(&occ, (const void*)lstm_fused, 256, 0);
    bool fused_ok = (occ >= 2) && (ws_size == 0 || ws_size >= need);
    if (fused_ok) {
        const f16* xgp = XG; const f16* w0p = Wh0h; const f16* w1p = W1h; const f16* wh1p = Wh1h;
        const float* b1p = b1; f16* bA = h1; f16* bB = h2;
        float* op = (float*)d_out; unsigned* bp = bar;
        void* args[] = { (void*)&xgp, (void*)&w0p, (void*)&w1p, (void*)&wh1p,
                         (void*)&b1p, (void*)&bA, (void*)&bB, (void*)&op, (void*)&bp };
        hipError_t e = hipLaunchCooperativeKernel((const void*)lstm_fused, dim3(512), dim3(256), args, 0, stream);
        fused_ok = (e == hipSuccess);
    }
    if (!fused_ok) {
        {
            const f16* xgp = XG; const f16* whp = Wh0h; f16* hp = h1;
            float* op = nullptr; unsigned* bp = bar;
            void* args[] = { (void*)&xgp, (void*)&whp, (void*)&hp, (void*)&op, (void*)&bp };
            (void)hipLaunchCooperativeKernel((const void*)lstm_layer, dim3(256), dim3(256), args, 0, stream);
        }
        gemm_f16<<<dim3(8192), dim3(256), 0, stream>>>(h1, W1h, b1, XG, HID, 2);
        {
            const f16* xgp = XG; const f16* whp = Wh1h; f16* hp = h1;
            float* op = (float*)d_out; unsigned* bp = bar + 1024;
            void* args[] = { (void*)&xgp, (void*)&whp, (void*)&hp, (void*)&op, (void*)&bp };
            (void)hipLaunchCooperativeKernel((const void*)lstm_layer, dim3(256), dim3(256), args, 0, stream);
        }
    }
}